// Round 18
// baseline (310.231 us; speedup 1.0000x reference)
//
#include <hip/hip_runtime.h>
#include <hip/hip_bf16.h>

// GCN: h1 = relu(Dinv (A+I) Dinv (x W1) + b1); h2 = relu(same with W2);
// out = mean-pool-by-graph(h2) @ Wl + bl.
// Identity: hs[u] = (xW)[u]*dinv[u]; conv[v] = dinv[v]*(hs[v] + sum_in hs[u]) + b.
// R18: sort pipe TLP doubled — R17 ran scatter/bfill at 1024thr x 1 block/CU
// (zero inter-block latency hiding). Now NB=512 buckets, 512 scatter blocks,
// 512 threads each -> 2 blocks/CU, half the per-block edges, 256-entry node
// scan. Cursor-scatter scheme (no global prefix scans) unchanged from R17.
// Convs/gemms/pool unchanged (proven 68us conv, absmax 9.77e-4).

#define HDIM 64
#define NB 512      // dst-range buckets (npb<=256 for N<=131072; src fits 17 bits)
#define SGRID 512   // blocks for scatter
#define STHR 512    // threads for scatter/bfill blocks

typedef __attribute__((ext_vector_type(8))) short short8;   // 8 bf16 (4 VGPRs)
typedef __attribute__((ext_vector_type(4))) float f32x4;
typedef __attribute__((ext_vector_type(2))) float f32x2;
union FragU { uint4 u; short8 s; };

static __device__ __forceinline__ unsigned bf16_bits(float f) {  // RNE
    unsigned u = __float_as_uint(f);
    return (u + 0x7fff + ((u >> 16) & 1)) >> 16;
}
static __device__ __forceinline__ float bflo(unsigned w) { return __uint_as_float(w << 16); }
static __device__ __forceinline__ float bfhi(unsigned w) { return __uint_as_float(w & 0xffff0000u); }

// ---------------- CSR build: cursor scatter + per-bucket fill ----------------

// Blocks 0..SGRID-1: LDS histogram of own chunk -> one global atomicAdd per
// bucket to reserve a run in bucket region [b*cap ...] -> re-read chunk
// (L2-warm) and scatter. Block SGRID: W swizzle prep.
__global__ __launch_bounds__(STHR) void k_scatter(const int* __restrict__ src,
        const int* __restrict__ dst, int* __restrict__ bcur, unsigned* __restrict__ ebuf,
        const float* __restrict__ W1, const float* __restrict__ W2,
        uint4* __restrict__ W1s, uint4* __restrict__ W2s,
        int N, int E, int npb, int chunk, int cap) {
    int tid = threadIdx.x;
    if (blockIdx.x == SGRID) {   // prep block: W swizzle only (needs 512 thr)
        int lane = tid & 63, ci = tid >> 6;   // ci in [0,8)
        for (int c2 = ci; c2 < 16; c2 += 8) { // W1: 4 ktiles x 4 ntiles
            int kt = c2 >> 2, nt = c2 & 3;
            int kbase = kt * 32 + (lane >> 4) * 8;
            int n = nt * 16 + (lane & 15);
            uint4 o; unsigned* op = (unsigned*)&o;
            for (int jj = 0; jj < 4; ++jj) {
                unsigned lo = bf16_bits(W1[(kbase + 2 * jj) * 64 + n]);
                unsigned hi = bf16_bits(W1[(kbase + 2 * jj + 1) * 64 + n]);
                op[jj] = lo | (hi << 16);
            }
            W1s[c2 * 64 + lane] = o;
        }
        {   // W2: K=64 -> 2 ktiles x 4 ntiles (ci 0..7)
            int kt = ci >> 2, nt = ci & 3;
            int kbase = kt * 32 + (lane >> 4) * 8;
            int n = nt * 16 + (lane & 15);
            uint4 o; unsigned* op = (unsigned*)&o;
            for (int jj = 0; jj < 4; ++jj) {
                unsigned lo = bf16_bits(W2[(kbase + 2 * jj) * 64 + n]);
                unsigned hi = bf16_bits(W2[(kbase + 2 * jj + 1) * 64 + n]);
                op[jj] = lo | (hi << 16);
            }
            W2s[ci * 64 + lane] = o;
        }
        return;
    }
    __shared__ int lh[4 * 257 + NB];          // hist (4x257) then reused tail
    __shared__ int base[NB], lcur[NB];
    int b = blockIdx.x;
    int e0 = b * chunk, e1 = min(E, e0 + chunk);
    int g0 = e0 >> 2, ng = (e1 - e0) >> 2;    // chunk %4==0 by construction
    const int4* dst4 = (const int4*)dst;
    const int4* src4 = (const int4*)src;
    // 4x-replicated histogram over 512 buckets: copy cp covers bucket t at
    // lh2[cp*? ] — use 4 copies of 512 with +1 pad stride 513 won't fit 4x513
    // ints in declared 1028+512... Use 2 copies of 513 instead (tid&1).
    int* lh2 = lh;                            // [2*513] within allocation
    for (int i = tid; i < 2 * 513; i += STHR) lh2[i] = 0;
    __syncthreads();
    int cp = (tid & 1) * 513;
    for (int g = g0 + tid; g < g0 + ng; g += STHR) {
        int4 d4 = dst4[g];
        atomicAdd(&lh2[cp + (unsigned)d4.x / (unsigned)npb], 1);
        atomicAdd(&lh2[cp + (unsigned)d4.y / (unsigned)npb], 1);
        atomicAdd(&lh2[cp + (unsigned)d4.z / (unsigned)npb], 1);
        atomicAdd(&lh2[cp + (unsigned)d4.w / (unsigned)npb], 1);
    }
    for (int e = e0 + ng * 4 + tid; e < e1; e += STHR)       // tail
        atomicAdd(&lh2[cp + (unsigned)dst[e] / (unsigned)npb], 1);
    __syncthreads();
    for (int t = tid; t < NB; t += STHR) {
        int tot = lh2[t] + lh2[513 + t];
        base[t] = t * cap + (tot ? atomicAdd(&bcur[t], tot) : 0);
        lcur[t] = 0;
    }
    __syncthreads();
    unsigned ebtot = (unsigned)NB * (unsigned)cap;           // memory-safety clamp
    for (int g = g0 + tid; g < g0 + ng; g += STHR) {         // re-read (L2-warm)
        int4 d4 = dst4[g];
        int4 s4 = src4[g];
        #define SCAT(D, S) {                                                   \
            unsigned bb = (unsigned)(D) / (unsigned)npb;                       \
            unsigned ld = (unsigned)(D) - bb * (unsigned)npb;                  \
            unsigned idx = (unsigned)base[bb] + (unsigned)atomicAdd(&lcur[bb], 1); \
            if (idx < ebtot) ebuf[idx] = (ld << 17) | (unsigned)(S); }
        SCAT(d4.x, s4.x) SCAT(d4.y, s4.y) SCAT(d4.z, s4.z) SCAT(d4.w, s4.w)
    }
    for (int e = e0 + ng * 4 + tid; e < e1; e += STHR) {     // tail
        SCAT(dst[e], src[e])
    }
    #undef SCAT
}

// One WG per bucket b: edges in [b*cap, b*cap + bcur[b]); node histogram ->
// padded scan -> meta/dinv + csr fill (rows padded to %8, dummy src = N).
// csr region for bucket b = [b*ccap ...). npb <= 256.
__global__ __launch_bounds__(STHR) void k_bfill(const unsigned* __restrict__ ebuf,
        const int* __restrict__ bcur, int4* __restrict__ meta,
        float* __restrict__ dinv, int* __restrict__ csr, int N, int npb,
        int cap, int ccap) {
    __shared__ int h[256], p[256], c[256];
    int b = blockIdx.x, tid = threadIdx.x;
    int vlo = b * npb;
    int vcnt = min(npb, N - vlo);
    if (vcnt <= 0) return;                    // uniform across block
    int ed0 = b * cap;
    int ed1 = ed0 + min(bcur[b], cap);
    for (int i = tid; i < 256; i += STHR) h[i] = 0;
    __syncthreads();
    for (int e = ed0 + tid; e < ed1; e += STHR)
        atomicAdd(&h[ebuf[e] >> 17], 1);
    __syncthreads();
    int pc = 0;
    if (tid < 256) {
        pc = (tid < vcnt) ? ((h[tid] + 7) & ~7) : 0;   // padded count
        p[tid] = pc;
    }
    __syncthreads();
    for (int off = 1; off < 256; off <<= 1) { // Hillis-Steele inclusive scan
        int v = 0;
        if (tid < 256 && tid >= off) v = p[tid - off];
        __syncthreads();
        if (tid < 256) p[tid] += v;
        __syncthreads();
    }
    int bb = b * ccap;                        // bucket's csr base
    if (tid < vcnt) {
        int excl = p[tid] - pc;
        int v = vlo + tid;
        float di = rsqrtf((float)(h[tid] + 1));
        meta[v] = make_int4(bb + excl, pc >> 3, __float_as_int(di), 0);
        dinv[v] = di;
        c[tid] = excl;
    }
    __syncthreads();
    for (int e = ed0 + tid; e < ed1; e += STHR) {
        unsigned ed = ebuf[e];
        int off = atomicAdd(&c[ed >> 17], 1);
        csr[bb + off] = (int)(ed & 0x1FFFFu);
    }
    __syncthreads();
    if (tid < vcnt) {                         // zero-row padding entries
        int excl = p[tid] - pc;
        for (int q = excl + h[tid]; q < excl + pc; ++q) csr[bb + q] = N;
    }
}

// ---------------- MFMA GEMMs ----------------
// D col=lane&15 (feature in ntile), row=(lane>>4)*4+r (node in 16).
#define MFMA_EPILOGUE(OUT)                                                     \
    {                                                                          \
        int col = lane & 15;                                                   \
        float dv[4];                                                           \
        for (int r = 0; r < 4; ++r) {                                          \
            int vr = v0 + quad * 4 + r;                                        \
            dv[r] = dinv[vr < n ? vr : (n - 1)];                               \
        }                                                                      \
        for (int nt = 0; nt < 4; ++nt)                                         \
            for (int r = 0; r < 4; ++r) {                                      \
                int vr = v0 + quad * 4 + r;                                    \
                float val = acc[nt][r] * dv[r];                                \
                float oth = __shfl_xor(val, 1, 64);                            \
                if (!(lane & 1) && vr < n)                                     \
                    OUT[(size_t)vr * 32 + nt * 8 + (col >> 1)] =               \
                        bf16_bits(val) | (bf16_bits(oth) << 16);               \
            }                                                                  \
    }

// hs1 = dinv * (X @ W1). X staged via wave-private LDS (coalesced 1KB loads).
// Block 0 also zeroes pad-row N of hsb (ebuf aliased it until k_bfill ran).
__global__ __launch_bounds__(256) void k_mgemm1(const float* __restrict__ X,
        const uint4* __restrict__ W1s, const float* __restrict__ dinv,
        unsigned* __restrict__ hsb, int n) {
    __shared__ float Xs[4][16 * 132];         // 16 rows, +4 pad per row
    if (blockIdx.x == 0 && threadIdx.x < 32) hsb[(size_t)n * 32 + threadIdx.x] = 0;
    int lane = threadIdx.x & 63, wv = threadIdx.x >> 6;
    int v0 = (blockIdx.x * 4 + wv) * 16;
    if (v0 >= n) return;                      // wave-uniform
    const float4* X4 = (const float4*)X;
#pragma unroll
    for (int i = 0; i < 8; ++i) {             // stage 16 rows (8KB), coalesced
        int gi = i * 64 + lane;
        int r = gi >> 5, c4 = gi & 31;
        int vr = v0 + r; if (vr >= n) vr = n - 1;
        float4 t = X4[(size_t)vr * 32 + c4];
        *(float4*)&Xs[wv][r * 132 + c4 * 4] = t;
    }
    // wave-private LDS: no barrier needed
    int quad = lane >> 4;
    const float* xr = &Xs[wv][(lane & 15) * 132 + quad * 8];
    f32x4 acc[4] = {f32x4{0,0,0,0}, f32x4{0,0,0,0}, f32x4{0,0,0,0}, f32x4{0,0,0,0}};
#pragma unroll
    for (int kt = 0; kt < 4; ++kt) {
        float4 xa = *(const float4*)(xr + kt * 32);
        float4 xb = *(const float4*)(xr + kt * 32 + 4);
        FragU a;
        a.u.x = bf16_bits(xa.x) | (bf16_bits(xa.y) << 16);
        a.u.y = bf16_bits(xa.z) | (bf16_bits(xa.w) << 16);
        a.u.z = bf16_bits(xb.x) | (bf16_bits(xb.y) << 16);
        a.u.w = bf16_bits(xb.z) | (bf16_bits(xb.w) << 16);
#pragma unroll
        for (int nt = 0; nt < 4; ++nt) {
            FragU bfr; bfr.u = W1s[(kt * 4 + nt) * 64 + lane];
            acc[nt] = __builtin_amdgcn_mfma_f32_16x16x32_bf16(a.s, bfr.s, acc[nt], 0, 0, 0);
        }
    }
    MFMA_EPILOGUE(hsb)
}

// hs2 = dinv * (h1 @ W2), h1 bf16-packed [N,32 uints], out same format.
// Block 0 also zeroes pad-row N of hsbB.
__global__ __launch_bounds__(256) void k_mgemm2(const unsigned* __restrict__ h1b,
        const uint4* __restrict__ W2s, const float* __restrict__ dinv,
        unsigned* __restrict__ hsbB, int n) {
    if (blockIdx.x == 0 && threadIdx.x < 32) hsbB[(size_t)n * 32 + threadIdx.x] = 0;
    int lane = threadIdx.x & 63, wv = threadIdx.x >> 6;
    int v0 = (blockIdx.x * 4 + wv) * 16;
    if (v0 >= n) return;
    int quad = lane >> 4;
    int vm = v0 + (lane & 15); if (vm >= n) vm = n - 1;
    const uint4* h4 = (const uint4*)h1b;
    f32x4 acc[4] = {f32x4{0,0,0,0}, f32x4{0,0,0,0}, f32x4{0,0,0,0}, f32x4{0,0,0,0}};
#pragma unroll
    for (int kt = 0; kt < 2; ++kt) {
        FragU a; a.u = h4[(size_t)vm * 8 + kt * 4 + quad];
#pragma unroll
        for (int nt = 0; nt < 4; ++nt) {
            FragU bfr; bfr.u = W2s[(kt * 4 + nt) * 64 + lane];
            acc[nt] = __builtin_amdgcn_mfma_f32_16x16x32_bf16(a.s, bfr.s, acc[nt], 0, 0, 0);
        }
    }
    MFMA_EPILOGUE(hsbB)
}

// ---------------- conv gather (wave per node, padded, shfl broadcast) -------
#define GATHER_BODY                                                            \
    const uint4* hs4p = (const uint4*)hsb;                                     \
    int o = lane & 7, oct = lane >> 3;                                         \
    int4 mt = meta[v];                                                         \
    int rs = mt.x, nb = mt.y;                                                  \
    float dv = __int_as_float(mt.z);                                           \
    f32x2 A0 = {0.f,0.f}, A1 = {0.f,0.f}, A2 = {0.f,0.f}, A3 = {0.f,0.f};      \
    if (oct == 0) {                                                            \
        uint4 s = hs4p[(size_t)v * 8 + o];                                     \
        A0 = (f32x2){bflo(s.x), bfhi(s.x)};                                    \
        A1 = (f32x2){bflo(s.y), bfhi(s.y)};                                    \
        A2 = (f32x2){bflo(s.z), bfhi(s.z)};                                    \
        A3 = (f32x2){bflo(s.w), bfhi(s.w)};                                    \
    }                                                                          \
    for (int base = 0; base < nb; base += 8) {                                 \
        int idx = csr[rs + base * 8 + lane];  /* overread ok: csr has slack */ \
        int m = nb - base; if (m > 8) m = 8;  /* wave-uniform */               \
        uint4 wb[8];                                                           \
        _Pragma("unroll")                                                      \
        for (int i = 0; i < 8; ++i)                                            \
            if (i < m) {                                                       \
                int u = __shfl(idx, i * 8 + oct, 64);                          \
                wb[i] = hs4p[(size_t)u * 8 + o];                               \
            }                                                                  \
        _Pragma("unroll")                                                      \
        for (int i = 0; i < 8; ++i)                                            \
            if (i < m) {                                                       \
                A0 += (f32x2){bflo(wb[i].x), bfhi(wb[i].x)};                   \
                A1 += (f32x2){bflo(wb[i].y), bfhi(wb[i].y)};                   \
                A2 += (f32x2){bflo(wb[i].z), bfhi(wb[i].z)};                   \
                A3 += (f32x2){bflo(wb[i].w), bfhi(wb[i].w)};                   \
            }                                                                  \
    }                                                                          \
    A0.x += __shfl_xor(A0.x, 8, 64); A0.x += __shfl_xor(A0.x, 16, 64);         \
    A0.x += __shfl_xor(A0.x, 32, 64);                                          \
    A0.y += __shfl_xor(A0.y, 8, 64); A0.y += __shfl_xor(A0.y, 16, 64);         \
    A0.y += __shfl_xor(A0.y, 32, 64);                                          \
    A1.x += __shfl_xor(A1.x, 8, 64); A1.x += __shfl_xor(A1.x, 16, 64);         \
    A1.x += __shfl_xor(A1.x, 32, 64);                                          \
    A1.y += __shfl_xor(A1.y, 8, 64); A1.y += __shfl_xor(A1.y, 16, 64);         \
    A1.y += __shfl_xor(A1.y, 32, 64);                                          \
    A2.x += __shfl_xor(A2.x, 8, 64); A2.x += __shfl_xor(A2.x, 16, 64);         \
    A2.x += __shfl_xor(A2.x, 32, 64);                                          \
    A2.y += __shfl_xor(A2.y, 8, 64); A2.y += __shfl_xor(A2.y, 16, 64);         \
    A2.y += __shfl_xor(A2.y, 32, 64);                                          \
    A3.x += __shfl_xor(A3.x, 8, 64); A3.x += __shfl_xor(A3.x, 16, 64);         \
    A3.x += __shfl_xor(A3.x, 32, 64);                                          \
    A3.y += __shfl_xor(A3.y, 8, 64); A3.y += __shfl_xor(A3.y, 16, 64);         \
    A3.y += __shfl_xor(A3.y, 32, 64);                                          \
    float4 bb0 = ((const float4*)bias)[2 * o];                                 \
    float4 bb1 = ((const float4*)bias)[2 * o + 1];                             \
    float r0 = fmaxf(fmaf(dv, A0.x, bb0.x), 0.f);                              \
    float r1 = fmaxf(fmaf(dv, A0.y, bb0.y), 0.f);                              \
    float r2 = fmaxf(fmaf(dv, A1.x, bb0.z), 0.f);                              \
    float r3 = fmaxf(fmaf(dv, A1.y, bb0.w), 0.f);                              \
    float r4 = fmaxf(fmaf(dv, A2.x, bb1.x), 0.f);                              \
    float r5 = fmaxf(fmaf(dv, A2.y, bb1.y), 0.f);                              \
    float r6 = fmaxf(fmaf(dv, A3.x, bb1.z), 0.f);                              \
    float r7 = fmaxf(fmaf(dv, A3.y, bb1.w), 0.f);

// conv1: gather hs1, h1 = relu(dinv*acc + b1), store h1 bf16-packed.
__global__ void k_conv1(const unsigned* __restrict__ hsb, const int4* __restrict__ meta,
                        const int* __restrict__ csr, const float* __restrict__ bias,
                        unsigned* __restrict__ h1b, int n) {
    int v = (blockIdx.x * 256 + threadIdx.x) >> 6;
    int lane = threadIdx.x & 63;
    if (v >= n) return;
    GATHER_BODY
    if (oct == 0) {
        uint4 pk;
        pk.x = bf16_bits(r0) | (bf16_bits(r1) << 16);
        pk.y = bf16_bits(r2) | (bf16_bits(r3) << 16);
        pk.z = bf16_bits(r4) | (bf16_bits(r5) << 16);
        pk.w = bf16_bits(r6) | (bf16_bits(r7) << 16);
        ((uint4*)h1b)[(size_t)v * 8 + o] = pk;
    }
}

// conv2 + head: gather hs2, h2 = relu(dinv*acc + b2), z[v] = h2 @ Wl.
__global__ void k_conv_out(const unsigned* __restrict__ hsb, const int4* __restrict__ meta,
                           const int* __restrict__ csr, const float* __restrict__ bias,
                           const float* __restrict__ Wl, float2* __restrict__ z, int n) {
    int v = (blockIdx.x * 256 + threadIdx.x) >> 6;
    int lane = threadIdx.x & 63;
    if (v >= n) return;
    GATHER_BODY
    const float4* Wl4 = (const float4*)Wl;    // [64][2] -> 2 rows per float4
    float4 wA = Wl4[4 * o + 0];
    float4 wB = Wl4[4 * o + 1];
    float4 wC = Wl4[4 * o + 2];
    float4 wD = Wl4[4 * o + 3];
    float c0 = r0*wA.x + r1*wA.z + r2*wB.x + r3*wB.z + r4*wC.x + r5*wC.z + r6*wD.x + r7*wD.z;
    float c1 = r0*wA.y + r1*wA.w + r2*wB.y + r3*wB.w + r4*wC.y + r5*wC.w + r6*wD.y + r7*wD.w;
    c0 += __shfl_xor(c0, 1, 64); c1 += __shfl_xor(c1, 1, 64);
    c0 += __shfl_xor(c0, 2, 64); c1 += __shfl_xor(c1, 2, 64);
    c0 += __shfl_xor(c0, 4, 64); c1 += __shfl_xor(c1, 4, 64);
    if (lane == 0) z[v] = make_float2(c0, c1);
}

static __device__ __forceinline__ int lower_bound(const int* __restrict__ a, int n, int key) {
    int lo = 0, hi = n;
    while (lo < hi) {
        int mid = (lo + hi) >> 1;
        if (a[mid] < key) lo = mid + 1; else hi = mid;
    }
    return lo;
}

// One wave per graph: out[g] = mean(z[lo:hi]) + bl  (batch sorted).
__global__ void k_pool_z(const float2* __restrict__ z, const int* __restrict__ batch,
                         const float* __restrict__ bl, float* __restrict__ out, int N, int B) {
    int g = (blockIdx.x * 256 + threadIdx.x) >> 6;
    int lane = threadIdx.x & 63;
    if (g >= B) return;
    int lo = lower_bound(batch, N, g);
    int hi = lower_bound(batch, N, g + 1);
    float c0 = 0.f, c1 = 0.f;
    for (int v = lo + lane; v < hi; v += 64) {
        float2 t = z[v];
        c0 += t.x; c1 += t.y;
    }
    #pragma unroll
    for (int off = 32; off; off >>= 1) {
        c0 += __shfl_xor(c0, off, 64);
        c1 += __shfl_xor(c1, off, 64);
    }
    if (lane == 0) {
        float inv = 1.0f / fmaxf((float)(hi - lo), 1.0f);
        out[g * 2 + 0] = c0 * inv + bl[0];
        out[g * 2 + 1] = c1 * inv + bl[1];
    }
}

extern "C" void kernel_launch(void* const* d_in, const int* in_sizes, int n_in,
                              void* d_out, int out_size, void* d_ws, size_t ws_size,
                              hipStream_t stream) {
    const float* x  = (const float*)d_in[0];   // [N,128] f32
    const int* edge = (const int*)d_in[1];     // [2,E] i32
    const int* batch= (const int*)d_in[2];     // [N] i32 (sorted)
    const float* W1 = (const float*)d_in[3];   // [128,64]
    const float* b1 = (const float*)d_in[4];   // [64]
    const float* W2 = (const float*)d_in[5];   // [64,64]
    const float* b2 = (const float*)d_in[6];   // [64]
    const float* Wl = (const float*)d_in[7];   // [64,2]
    const float* bl = (const float*)d_in[8];   // [2]
    float* out = (float*)d_out;

    const int N = in_sizes[2];
    const int E = in_sizes[1] / 2;
    const int B = out_size / 2;
    const int* srcp = edge;
    const int* dstp = edge + E;
    const int npb = (N + NB - 1) / NB;         // nodes per bucket (196 @ N=100K, <=256)
    const int mean = (E + NB - 1) / NB;        // ~6250 edges/bucket
    const int cap  = ((mean + mean / 2 + 1536) + 1023) & ~1023;  // ~1.7x mean
    const int ccap = ((cap + 7 * npb + 128) + 127) & ~127;       // csr ints per bucket

    // workspace carve-up (256B aligned); ~68 MB
    char* w = (char*)d_ws;
    auto carve = [&](size_t bytes) { void* p = (void*)w; w += (bytes + 255) & ~(size_t)255; return p; };
    int4*     meta    = (int4*)carve((size_t)N * 16);
    float*    dinv    = (float*)carve((size_t)N * 4);
    int*      bcur    = (int*)carve((NB + 8) * 4);
    uint4*    W1s     = (uint4*)carve(16 * 64 * 16);
    uint4*    W2s     = (uint4*)carve(8 * 64 * 16);
    int*      csr     = (int*)carve(((size_t)NB * ccap + 256) * 4);  // fixed-cap buckets
    // ebuf aliases hsbA+h1b (NB*cap*4 ~ 23MB < 25.6MB): both are written
    // only after k_bfill consumed ebuf. Pad-rows N zeroed by mgemm1/mgemm2.
    unsigned* hsbA    = (unsigned*)carve(((size_t)N + 1) * 32 * 4);
    unsigned* h1b     = (unsigned*)carve(((size_t)N + 1) * 32 * 4);  // bf16x2 relu'd h1
    unsigned* hsbB    = (unsigned*)carve(((size_t)N + 1) * 32 * 4);  // bf16x2 hs layer2
    float2*   zbuf    = (float2*)carve((size_t)N * 8);               // per-node head output
    unsigned* ebuf    = hsbA;

    int chunk = ((E + SGRID - 1) / SGRID + 3) & ~3;  // edges per block, %4==0
    int wbl = (N + 3) / 4;                      // 4 waves (nodes) per 256-thread block
    int gbl = (N + 63) / 64;                    // 64 nodes per MFMA-gemm block

    hipMemsetAsync(bcur, 0, NB * 4, stream);
    k_scatter<<<SGRID + 1, STHR, 0, stream>>>(srcp, dstp, bcur, ebuf,
                                              W1, W2, W1s, W2s, N, E, npb, chunk, cap);
    k_bfill<<<NB, STHR, 0, stream>>>(ebuf, bcur, meta, dinv, csr, N, npb, cap, ccap);

    k_mgemm1<<<gbl, 256, 0, stream>>>(x, W1s, dinv, hsbA, N);
    k_conv1<<<wbl, 256, 0, stream>>>(hsbA, meta, csr, b1, h1b, N);
    k_mgemm2<<<gbl, 256, 0, stream>>>(h1b, W2s, dinv, hsbB, N);
    k_conv_out<<<wbl, 256, 0, stream>>>(hsbB, meta, csr, b2, Wl, zbuf, N);

    k_pool_z<<<(B * 64 + 255) / 256, 256, 0, stream>>>(zbuf, batch, bl, out, N, B);
}